// Round 8
// baseline (357.969 us; speedup 1.0000x reference)
//
#include <hip/hip_runtime.h>
#include <stdint.h>

#define B_  64
#define H_  32
#define D_  4096
#define KD  128
#define VD  128
#define M_  4095
#define M1_ 4096
#define NCHUNK 32
#define LOG2E 1.44269504088896f

// ---- workspace layout (float offsets) ----
#define WS_P      0ull
#define WS_Q      4456448ull
#define WS_STATS  4718592ull
#define WS_O      4849664ull
#define WS_OPART  5111808ull

#define WAITVL(n) asm volatile("s_waitcnt vmcnt(" #n ") lgkmcnt(0)" ::: "memory")
#define WAITL()  asm volatile("s_waitcnt lgkmcnt(0)" ::: "memory")
#define BAR()    __builtin_amdgcn_s_barrier()

typedef __attribute__((address_space(3))) char lds_char;
typedef const __attribute__((address_space(1))) char glb_char;

// ---------------- K1a: partial projections (q, k_new, v_new) ----------------
__global__ __launch_bounds__(256) void k_proj_partial(
    const float* __restrict__ x, const float* __restrict__ Wq,
    const float* __restrict__ Wk, const float* __restrict__ Wv,
    float* __restrict__ P) {
  __shared__ float xs[64][260];   // padded: 2-way max on column reads
  const int dc = blockIdx.x;
  const int hx = blockIdx.y;
  const int t  = threadIdx.x;
  const float* xsrc = x + dc * 256;
  #pragma unroll
  for (int j = 0; j < 16; ++j) {
    int f = t + 256 * j;
    int row = f >> 6, c4 = f & 63;
    *(float4*)&xs[row][c4 * 4] =
        *(const float4*)(xsrc + (size_t)row * D_ + c4 * 4);
  }
  __syncthreads();
  const int bq = t >> 4;
  const int kg = t & 15;
  const int b0 = bq * 4;
  const float* W = (hx < H_) ? (Wq + (size_t)hx * D_ * KD)
                             : ((hx == H_) ? Wk : Wv);
  const float* wp = W + (size_t)(dc * 256) * KD + kg * 8;
  float acc[4][8];
  #pragma unroll
  for (int i = 0; i < 4; ++i)
    #pragma unroll
    for (int j = 0; j < 8; ++j) acc[i][j] = 0.f;
  #pragma unroll 8
  for (int d = 0; d < 256; ++d) {
    float4 w0 = *(const float4*)(wp + (size_t)d * KD);
    float4 w1 = *(const float4*)(wp + (size_t)d * KD + 4);
    float xv[4];
    #pragma unroll
    for (int i = 0; i < 4; ++i) xv[i] = xs[b0 + i][d];
    #pragma unroll
    for (int i = 0; i < 4; ++i) {
      acc[i][0] += xv[i] * w0.x; acc[i][1] += xv[i] * w0.y;
      acc[i][2] += xv[i] * w0.z; acc[i][3] += xv[i] * w0.w;
      acc[i][4] += xv[i] * w1.x; acc[i][5] += xv[i] * w1.y;
      acc[i][6] += xv[i] * w1.z; acc[i][7] += xv[i] * w1.w;
    }
  }
  #pragma unroll
  for (int i = 0; i < 4; ++i) {
    size_t base = ((size_t)(dc * 64 + b0 + i) * 34 + hx) * KD + kg * 8;
    *(float4*)&P[base]     = make_float4(acc[i][0], acc[i][1], acc[i][2], acc[i][3]);
    *(float4*)&P[base + 4] = make_float4(acc[i][4], acc[i][5], acc[i][6], acc[i][7]);
  }
}

// ---------------- K1b: reduce partials -> q, Kc[.,M,:], Vc[.,M,:] ----------
__global__ __launch_bounds__(256) void k_proj_reduce(
    const float* __restrict__ P, float* __restrict__ q,
    float* __restrict__ Kc, float* __restrict__ Vc) {
  int i = blockIdx.x * 256 + threadIdx.x;
  int k = i & 127;
  int hx = (i >> 7) % 34;
  int b = i / (128 * 34);
  float s = 0.f;
  #pragma unroll
  for (int dc = 0; dc < 16; ++dc)
    s += P[(size_t)dc * (64 * 34 * 128) + (size_t)(b * 34 + hx) * 128 + k];
  if (hx < H_)       q[((size_t)b * H_ + hx) * KD + k] = s;
  else if (hx == H_) Kc[((size_t)b * M1_ + M_) * KD + k] = s;
  else               Vc[((size_t)b * M1_ + M_) * VD + k] = s;
}

// ---------------- K2: flash attention ---------------------------------------
// K phase: 4 tiles of 32 rows via global_load_lds 2-buffer ring, counted
// vmcnt; logits accumulate in registers; in-register softmax.
// V phase: NO staging — PV reads V rows directly from global (coalesced
// 512B/row, L1-shared across the block's waves), Vc copy from the same
// registers, zero barriers, waves free-run at HBM rate.
__device__ __forceinline__ void stage_issue(
    const float* src, const float* app_row, float* lbuf, int m_lo, int t) {
  const int wb = t & ~63;   // wave-uniform thread base
  #pragma unroll
  for (int j = 0; j < 4; ++j) {
    int f = j * 256 + t;
    int r = f >> 5, p = f & 31;
    int m = m_lo + r;
    int g4 = p ^ (r & 7);
    const float* gp = (m < M_) ? (src + (size_t)m * 128 + g4 * 4)
                               : (app_row + g4 * 4);
    __builtin_amdgcn_global_load_lds(
        (glb_char*)gp, (lds_char*)(lbuf + (size_t)(j * 256 + wb) * 4),
        16, 0, 0);
  }
}

__device__ __forceinline__ void copy_out(
    const float* lbuf, float* dst, int m_lo, int t) {
  const int r = t >> 3;
  const int m = m_lo + r;
  float* drow = dst + (size_t)m * 128;
  #pragma unroll
  for (int jj = 0; jj < 4; ++jj) {
    int g4 = (t & 7) + jj * 8;
    int p = g4 ^ (r & 7);
    float4 v = *(const float4*)&lbuf[(r * 32 + p) * 4];
    *(float4*)(drow + g4 * 4) = v;   // m==M_ rewrites identical bytes
  }
}

__global__ __launch_bounds__(256, 3) void k_flash(
    const float* __restrict__ prevK, const float* __restrict__ prevV,
    const float* __restrict__ q, float* __restrict__ Kc, float* __restrict__ Vc,
    float* __restrict__ o_part, float* __restrict__ stats) {
  __shared__ float buf[2][32 * 128];   // 32 KB K ring
  __shared__ float upool[4608];        // K phase: qs[32][132]; then wl[128][36]
  const int chunk = blockIdx.x;
  const int b = blockIdx.y;
  const int t = threadIdx.x;
  const int m0 = chunk * 128;

  const float* kbase = prevK + (size_t)b * M_ * KD;
  const float* vbase = prevV + (size_t)b * M_ * VD;
  const float* kapp  = Kc + ((size_t)b * M1_ + M_) * KD;
  const float* vapp  = Vc + ((size_t)b * M1_ + M_) * VD;
  float* kc = Kc + (size_t)b * M1_ * KD;
  float* vc = Vc + (size_t)b * M1_ * VD;

  // q -> regs; K0,K1 staged in between; q -> LDS (stride 132)
  const float* qsrc = q + (size_t)b * H_ * KD;
  float4 qv4[4];
  #pragma unroll
  for (int j = 0; j < 4; ++j) {
    int f = j * 256 + t;
    qv4[j] = *(const float4*)(qsrc + (size_t)(f >> 5) * KD + (f & 31) * 4);
  }
  stage_issue(kbase, kapp, buf[0], m0, t);          // K0
  stage_issue(kbase, kapp, buf[1], m0 + 32, t);     // K1
  #pragma unroll
  for (int j = 0; j < 4; ++j) {
    int f = j * 256 + t;
    *(float4*)&upool[(f >> 5) * 132 + (f & 31) * 4] = qv4[j];
  }

  const int mg = t & 15, hg = t >> 4, h0 = hg * 2;      // logits mapping
  const int v4 = t & 31, hoct = t >> 5, h0v = hoct * 4; // PV mapping

  float accL0[8], accL1[8];   // logits regs: [tile*2 + i], m = tile*32+mg+16i

#define LOGITS_TILE(S, BUFI)                                                  \
  {                                                                           \
    const float* lb = buf[BUFI];                                              \
    float c00 = 0.f, c01 = 0.f, c10 = 0.f, c11 = 0.f;                         \
    const int sw = (mg & 7);                                                  \
    _Pragma("unroll 4")                                                       \
    for (int k4 = 0; k4 < 32; ++k4) {                                         \
      int p = (k4 ^ sw) * 4;                                                  \
      float4 qa = *(const float4*)&upool[h0 * 132 + k4 * 4];                  \
      float4 qb = *(const float4*)&upool[(h0 + 1) * 132 + k4 * 4];            \
      float4 k0v = *(const float4*)&lb[mg * 128 + p];                         \
      float4 k1v = *(const float4*)&lb[(mg + 16) * 128 + p];                  \
      c00 += qa.x*k0v.x + qa.y*k0v.y + qa.z*k0v.z + qa.w*k0v.w;               \
      c01 += qa.x*k1v.x + qa.y*k1v.y + qa.z*k1v.z + qa.w*k1v.w;               \
      c10 += qb.x*k0v.x + qb.y*k0v.y + qb.z*k0v.z + qb.w*k0v.w;               \
      c11 += qb.x*k1v.x + qb.y*k1v.y + qb.z*k1v.z + qb.w*k1v.w;               \
    }                                                                         \
    accL0[(S) * 2]     = c00;                                                 \
    accL0[(S) * 2 + 1] = c01;                                                 \
    accL1[(S) * 2]     = c10;                                                 \
    accL1[(S) * 2 + 1] = c11;                                                 \
  }

  // ---- K phase: ring of 2, counted vmcnt (never 0 mid-phase) ----
  WAITVL(4); BAR();                                 // K0 ready (K1 in flight)
  LOGITS_TILE(0, 0);
  copy_out(buf[0], kc, m0, t);                      // S0: +4 stores
  WAITL(); BAR();                                   // buf0 reads done everywhere

  stage_issue(kbase, kapp, buf[0], m0 + 64, t);     // K2
  WAITVL(8); BAR();                                 // K1 ready (S0+K2 = 8 newer)
  LOGITS_TILE(1, 1);
  copy_out(buf[1], kc, m0 + 32, t);                 // S1
  WAITL(); BAR();                                   // buf1 reads done

  stage_issue(kbase, kapp, buf[1], m0 + 96, t);     // K3
  WAITVL(8); BAR();                                 // K2 ready (S1+K3 = 8 newer)
  LOGITS_TILE(2, 0);
  copy_out(buf[0], kc, m0 + 64, t);                 // S2
  WAITVL(4); BAR();                                 // K3 ready (S2 = 4 newer)
  LOGITS_TILE(3, 1);
  copy_out(buf[1], kc, m0 + 96, t);                 // S3
  WAITL(); BAR();                                   // all qs reads done -> upool = wl

  // ---- in-register softmax over the 16-lane mg-group ----
  {
    float mx0 = -3.402823466e38f, mx1 = -3.402823466e38f;
    #pragma unroll
    for (int j = 0; j < 8; ++j) {
      mx0 = fmaxf(mx0, accL0[j]);
      mx1 = fmaxf(mx1, accL1[j]);
    }
    #pragma unroll
    for (int off = 1; off <= 8; off <<= 1) {
      mx0 = fmaxf(mx0, __shfl_xor(mx0, off));
      mx1 = fmaxf(mx1, __shfl_xor(mx1, off));
    }
    float s0 = 0.f, s1 = 0.f;
    #pragma unroll
    for (int j = 0; j < 8; ++j) {
      float e0 = exp2f((accL0[j] - mx0) * LOG2E); accL0[j] = e0; s0 += e0;
      float e1 = exp2f((accL1[j] - mx1) * LOG2E); accL1[j] = e1; s1 += e1;
    }
    #pragma unroll
    for (int off = 1; off <= 8; off <<= 1) {
      s0 += __shfl_xor(s0, off);
      s1 += __shfl_xor(s1, off);
    }
    #pragma unroll
    for (int s = 0; s < 4; ++s)
      #pragma unroll
      for (int i = 0; i < 2; ++i) {
        int m = s * 32 + mg + 16 * i;
        upool[m * 36 + h0]     = accL0[s * 2 + i];
        upool[m * 36 + h0 + 1] = accL1[s * 2 + i];
      }
    if (mg == 0) {
      size_t sb0 = (((size_t)b * H_ + h0) * NCHUNK + chunk) * 2;
      *(float2*)&stats[sb0] = make_float2(mx0, s0);
      size_t sb1 = (((size_t)b * H_ + h0 + 1) * NCHUNK + chunk) * 2;
      *(float2*)&stats[sb1] = make_float2(mx1, s1);
    }
  }
  WAITL(); BAR();   // wl visible to all waves

  // ---- V phase: global-direct PV, barrier-free ----
  {
    float4 a0 = {0,0,0,0}, a1 = {0,0,0,0}, a2 = {0,0,0,0}, a3 = {0,0,0,0};
    #pragma unroll 8
    for (int mm = 0; mm < 128; ++mm) {
      const int mv = m0 + mm;
      const float* vrow = (mv < M_) ? (vbase + (size_t)mv * VD) : vapp;
      float4 gv = *(const float4*)(vrow + v4 * 4);          // coalesced 512B/row
      if (hoct == 0 && mv < M_)
        *(float4*)(vc + (size_t)mv * VD + v4 * 4) = gv;     // Vc copy
      float4 w4 = *(const float4*)&upool[mm * 36 + h0v];    // broadcast
      a0.x += w4.x*gv.x; a0.y += w4.x*gv.y; a0.z += w4.x*gv.z; a0.w += w4.x*gv.w;
      a1.x += w4.y*gv.x; a1.y += w4.y*gv.y; a1.z += w4.y*gv.z; a1.w += w4.y*gv.w;
      a2.x += w4.z*gv.x; a2.y += w4.z*gv.y; a2.z += w4.z*gv.z; a2.w += w4.z*gv.w;
      a3.x += w4.w*gv.x; a3.y += w4.w*gv.y; a3.z += w4.w*gv.z; a3.w += w4.w*gv.w;
    }
    size_t base = ((size_t)(chunk * B_ + b) * H_ + h0v) * VD + v4 * 4;
    *(float4*)&o_part[base]          = a0;
    *(float4*)&o_part[base + VD]     = a1;
    *(float4*)&o_part[base + 2 * VD] = a2;
    *(float4*)&o_part[base + 3 * VD] = a3;
  }
#undef LOGITS_TILE
}

// ---------------- K3: flash combine -> o -----------------------------------
__global__ __launch_bounds__(128) void k_combine(
    const float* __restrict__ o_part, const float* __restrict__ stats,
    float* __restrict__ o) {
  const int bh = blockIdx.x;
  const int t = threadIdx.x;
  __shared__ float st[64];
  if (t < 64) st[t] = stats[(size_t)bh * 64 + t];
  __syncthreads();
  float M = -3.402823466e38f;
  #pragma unroll
  for (int c = 0; c < NCHUNK; ++c) M = fmaxf(M, st[2 * c]);
  float wc[NCHUNK];
  float denom = 0.f;
  #pragma unroll
  for (int c = 0; c < NCHUNK; ++c) {
    float e = exp2f((st[2 * c] - M) * LOG2E);
    wc[c] = e;
    denom += st[2 * c + 1] * e;
  }
  const float inv = 1.0f / denom;
  const int b = bh >> 5, h = bh & 31;
  float acc = 0.f;
  #pragma unroll 4
  for (int c = 0; c < NCHUNK; ++c)
    acc += wc[c] * o_part[((size_t)(c * B_ + b) * H_ + h) * VD + t];
  o[(size_t)bh * VD + t] = acc * inv;
}

// ---------------- K5: partial y = o . Wo -----------------------------------
__global__ __launch_bounds__(256) void k_out_partial(
    const float* __restrict__ o, const float* __restrict__ Wo,
    float* __restrict__ Py) {
  __shared__ float os[64][260];   // padded
  const int dc = blockIdx.x;
  const int hvc = blockIdx.y;
  const int t = threadIdx.x;
  #pragma unroll
  for (int j = 0; j < 16; ++j) {
    int f = t + 256 * j;
    int row = f >> 6, c4 = f & 63;
    *(float4*)&os[row][c4 * 4] =
        *(const float4*)(o + (size_t)row * 4096 + hvc * 256 + c4 * 4);
  }
  __syncthreads();
  const int bq = t >> 4, dg = t & 15;
  const int b0 = bq * 4;
  const float* wp = Wo + (size_t)(hvc * 256) * D_ + dc * 128 + dg * 8;
  float acc[4][8];
  #pragma unroll
  for (int i = 0; i < 4; ++i)
    #pragma unroll
    for (int j = 0; j < 8; ++j) acc[i][j] = 0.f;
  #pragma unroll 8
  for (int hv = 0; hv < 256; ++hv) {
    float4 w0 = *(const float4*)(wp + (size_t)hv * D_);
    float4 w1 = *(const float4*)(wp + (size_t)hv * D_ + 4);
    float ov[4];
    #pragma unroll
    for (int i = 0; i < 4; ++i) ov[i] = os[b0 + i][hv];
    #pragma unroll
    for (int i = 0; i < 4; ++i) {
      acc[i][0] += ov[i] * w0.x; acc[i][1] += ov[i] * w0.y;
      acc[i][2] += ov[i] * w0.z; acc[i][3] += ov[i] * w0.w;
      acc[i][4] += ov[i] * w1.x; acc[i][5] += ov[i] * w1.y;
      acc[i][6] += ov[i] * w1.z; acc[i][7] += ov[i] * w1.w;
    }
  }
  #pragma unroll
  for (int i = 0; i < 4; ++i) {
    size_t base = ((size_t)hvc * 64 + b0 + i) * 4096 + dc * 128 + dg * 8;
    *(float4*)&Py[base]     = make_float4(acc[i][0], acc[i][1], acc[i][2], acc[i][3]);
    *(float4*)&Py[base + 4] = make_float4(acc[i][4], acc[i][5], acc[i][6], acc[i][7]);
  }
}

// ---------------- K5b: reduce partial y ------------------------------------
__global__ __launch_bounds__(256) void k_yreduce(
    const float* __restrict__ Py, float* __restrict__ y) {
  int i = blockIdx.x * 256 + threadIdx.x;
  float s = 0.f;
  #pragma unroll
  for (int c = 0; c < 16; ++c) s += Py[(size_t)c * 262144 + i];
  y[i] = s;
}

extern "C" void kernel_launch(void* const* d_in, const int* in_sizes, int n_in,
                              void* d_out, int out_size, void* d_ws, size_t ws_size,
                              hipStream_t stream) {
  const float* x     = (const float*)d_in[0];
  const float* prevK = (const float*)d_in[1];
  const float* prevV = (const float*)d_in[2];
  const float* Wq    = (const float*)d_in[3];
  const float* Wk    = (const float*)d_in[4];
  const float* Wv    = (const float*)d_in[5];
  const float* Wo    = (const float*)d_in[6];

  float* y  = (float*)d_out;
  float* Kc = y + (size_t)B_ * D_;
  float* Vc = Kc + (size_t)B_ * M1_ * KD;

  float* ws     = (float*)d_ws;
  float* P      = ws + WS_P;
  float* q      = ws + WS_Q;
  float* stats  = ws + WS_STATS;
  float* o      = ws + WS_O;
  float* o_part = ws + WS_OPART;

  k_proj_partial<<<dim3(16, 34), 256, 0, stream>>>(x, Wq, Wk, Wv, P);
  k_proj_reduce<<<1088, 256, 0, stream>>>(P, q, Kc, Vc);
  k_flash<<<dim3(32, 64), 256, 0, stream>>>(prevK, prevV, q, Kc, Vc, o_part, stats);
  k_combine<<<2048, 128, 0, stream>>>(o_part, stats, o);
  k_out_partial<<<dim3(32, 16), 256, 0, stream>>>(o, Wo, P);
  k_yreduce<<<1024, 256, 0, stream>>>(P, y);
}

// Round 9
// 263.790 us; speedup vs baseline: 1.3570x; 1.3570x over previous
//
#include <hip/hip_runtime.h>
#include <stdint.h>

#define B_  64
#define H_  32
#define D_  4096
#define KD  128
#define VD  128
#define M_  4095
#define M1_ 4096
#define NCHUNK 32
#define LOG2E 1.44269504088896f

// ---- workspace layout (float offsets) ----
#define WS_P      0ull
#define WS_Q      4456448ull
#define WS_STATS  4718592ull
#define WS_O      4849664ull
#define WS_OPART  5111808ull

#define WAITVL(n) asm volatile("s_waitcnt vmcnt(" #n ") lgkmcnt(0)" ::: "memory")
#define WAITL()  asm volatile("s_waitcnt lgkmcnt(0)" ::: "memory")
#define BAR()    __builtin_amdgcn_s_barrier()

typedef __attribute__((address_space(3))) char lds_char;
typedef const __attribute__((address_space(1))) char glb_char;

// ---------------- K1a: partial projections (q, k_new, v_new) ----------------
__global__ __launch_bounds__(256) void k_proj_partial(
    const float* __restrict__ x, const float* __restrict__ Wq,
    const float* __restrict__ Wk, const float* __restrict__ Wv,
    float* __restrict__ P) {
  __shared__ float xs[64][260];   // padded: 2-way max on column reads
  const int dc = blockIdx.x;
  const int hx = blockIdx.y;
  const int t  = threadIdx.x;
  const float* xsrc = x + dc * 256;
  #pragma unroll
  for (int j = 0; j < 16; ++j) {
    int f = t + 256 * j;
    int row = f >> 6, c4 = f & 63;
    *(float4*)&xs[row][c4 * 4] =
        *(const float4*)(xsrc + (size_t)row * D_ + c4 * 4);
  }
  __syncthreads();
  const int bq = t >> 4;
  const int kg = t & 15;
  const int b0 = bq * 4;
  const float* W = (hx < H_) ? (Wq + (size_t)hx * D_ * KD)
                             : ((hx == H_) ? Wk : Wv);
  const float* wp = W + (size_t)(dc * 256) * KD + kg * 8;
  float acc[4][8];
  #pragma unroll
  for (int i = 0; i < 4; ++i)
    #pragma unroll
    for (int j = 0; j < 8; ++j) acc[i][j] = 0.f;
  #pragma unroll 8
  for (int d = 0; d < 256; ++d) {
    float4 w0 = *(const float4*)(wp + (size_t)d * KD);
    float4 w1 = *(const float4*)(wp + (size_t)d * KD + 4);
    float xv[4];
    #pragma unroll
    for (int i = 0; i < 4; ++i) xv[i] = xs[b0 + i][d];
    #pragma unroll
    for (int i = 0; i < 4; ++i) {
      acc[i][0] += xv[i] * w0.x; acc[i][1] += xv[i] * w0.y;
      acc[i][2] += xv[i] * w0.z; acc[i][3] += xv[i] * w0.w;
      acc[i][4] += xv[i] * w1.x; acc[i][5] += xv[i] * w1.y;
      acc[i][6] += xv[i] * w1.z; acc[i][7] += xv[i] * w1.w;
    }
  }
  #pragma unroll
  for (int i = 0; i < 4; ++i) {
    size_t base = ((size_t)(dc * 64 + b0 + i) * 34 + hx) * KD + kg * 8;
    *(float4*)&P[base]     = make_float4(acc[i][0], acc[i][1], acc[i][2], acc[i][3]);
    *(float4*)&P[base + 4] = make_float4(acc[i][4], acc[i][5], acc[i][6], acc[i][7]);
  }
}

// ---------------- K1b: reduce partials -> q, Kc[.,M,:], Vc[.,M,:] ----------
__global__ __launch_bounds__(256) void k_proj_reduce(
    const float* __restrict__ P, float* __restrict__ q,
    float* __restrict__ Kc, float* __restrict__ Vc) {
  int i = blockIdx.x * 256 + threadIdx.x;
  int k = i & 127;
  int hx = (i >> 7) % 34;
  int b = i / (128 * 34);
  float s = 0.f;
  #pragma unroll
  for (int dc = 0; dc < 16; ++dc)
    s += P[(size_t)dc * (64 * 34 * 128) + (size_t)(b * 34 + hx) * 128 + k];
  if (hx < H_)       q[((size_t)b * H_ + hx) * KD + k] = s;
  else if (hx == H_) Kc[((size_t)b * M1_ + M_) * KD + k] = s;
  else               Vc[((size_t)b * M1_ + M_) * VD + k] = s;
}

// ---------------- K2: flash attention, async-pipelined ---------------------
// 8 tiles of 32 rows (4 K, 4 V) via global_load_lds 2-buffer ring, counted
// vmcnt never drained to 0 mid-loop. Logits in registers, in-register
// softmax, qs/wl LDS union. copy_out reads LDS LINEARLY (conflict-free) and
// applies the inverse swizzle on the global store address (same 512B row ->
// coalescing unchanged).
__device__ __forceinline__ void stage_issue(
    const float* src, const float* app_row, float* lbuf, int m_lo, int t) {
  const int wb = t & ~63;   // wave-uniform thread base
  #pragma unroll
  for (int j = 0; j < 4; ++j) {
    int f = j * 256 + t;
    int r = f >> 5, p = f & 31;
    int m = m_lo + r;
    int g4 = p ^ (r & 7);
    const float* gp = (m < M_) ? (src + (size_t)m * 128 + g4 * 4)
                               : (app_row + g4 * 4);
    __builtin_amdgcn_global_load_lds(
        (glb_char*)gp, (lds_char*)(lbuf + (size_t)(j * 256 + wb) * 4),
        16, 0, 0);
  }
}

__device__ __forceinline__ void copy_out(
    const float* lbuf, float* dst, int m_lo, int t) {
  #pragma unroll
  for (int jj = 0; jj < 4; ++jj) {
    int f = jj * 256 + t;
    int r = f >> 5, p = f & 31;
    int g4 = p ^ (r & 7);                       // LDS[r][p] holds G[r][p^(r&7)]
    float4 v = *(const float4*)&lbuf[(size_t)f * 4];   // linear: conflict-free
    *(float4*)(dst + (size_t)(m_lo + r) * 128 + g4 * 4) = v;  // m==M_ rewrites same bytes
  }
}

__global__ __launch_bounds__(256, 3) void k_flash(
    const float* __restrict__ prevK, const float* __restrict__ prevV,
    const float* __restrict__ q, float* __restrict__ Kc, float* __restrict__ Vc,
    float* __restrict__ o_part, float* __restrict__ stats) {
  __shared__ float buf[2][32 * 128];   // 32 KB ring
  __shared__ float upool[4608];        // K phase: qs[32][132]; V phase: wl[128][36]
  const int chunk = blockIdx.x;
  const int b = blockIdx.y;
  const int t = threadIdx.x;
  const int m0 = chunk * 128;

  const float* kbase = prevK + (size_t)b * M_ * KD;
  const float* vbase = prevV + (size_t)b * M_ * VD;
  const float* kapp  = Kc + ((size_t)b * M1_ + M_) * KD;
  const float* vapp  = Vc + ((size_t)b * M1_ + M_) * VD;
  float* kc = Kc + (size_t)b * M1_ * KD;
  float* vc = Vc + (size_t)b * M1_ * VD;

  // q -> regs -> LDS (stride 132); K0 staged in between
  const float* qsrc = q + (size_t)b * H_ * KD;
  float4 qv4[4];
  #pragma unroll
  for (int j = 0; j < 4; ++j) {
    int f = j * 256 + t;
    qv4[j] = *(const float4*)(qsrc + (size_t)(f >> 5) * KD + (f & 31) * 4);
  }
  stage_issue(kbase, kapp, buf[0], m0, t);          // K0
  #pragma unroll
  for (int j = 0; j < 4; ++j) {
    int f = j * 256 + t;
    *(float4*)&upool[(f >> 5) * 132 + (f & 31) * 4] = qv4[j];
  }

  const int mg = t & 15, hg = t >> 4, h0 = hg * 2;      // logits mapping
  const int v4 = t & 31, hoct = t >> 5, h0v = hoct * 4; // PV mapping

  float accL0[8], accL1[8];   // logits regs: [tile*2 + i], m = tile*32+mg+16i

#define LOGITS_TILE(S, BUFI)                                                  \
  {                                                                           \
    const float* lb = buf[BUFI];                                              \
    float c00 = 0.f, c01 = 0.f, c10 = 0.f, c11 = 0.f;                         \
    const int sw = (mg & 7);                                                  \
    _Pragma("unroll 4")                                                       \
    for (int k4 = 0; k4 < 32; ++k4) {                                         \
      int p = (k4 ^ sw) * 4;                                                  \
      float4 qa = *(const float4*)&upool[h0 * 132 + k4 * 4];                  \
      float4 qb = *(const float4*)&upool[(h0 + 1) * 132 + k4 * 4];            \
      float4 k0v = *(const float4*)&lb[mg * 128 + p];                         \
      float4 k1v = *(const float4*)&lb[(mg + 16) * 128 + p];                  \
      c00 += qa.x*k0v.x + qa.y*k0v.y + qa.z*k0v.z + qa.w*k0v.w;               \
      c01 += qa.x*k1v.x + qa.y*k1v.y + qa.z*k1v.z + qa.w*k1v.w;               \
      c10 += qb.x*k0v.x + qb.y*k0v.y + qb.z*k0v.z + qb.w*k0v.w;               \
      c11 += qb.x*k1v.x + qb.y*k1v.y + qb.z*k1v.z + qb.w*k1v.w;               \
    }                                                                         \
    accL0[(S) * 2]     = c00;                                                 \
    accL0[(S) * 2 + 1] = c01;                                                 \
    accL1[(S) * 2]     = c10;                                                 \
    accL1[(S) * 2 + 1] = c11;                                                 \
  }

#define PV_TILE(S, BUFI)                                                      \
  {                                                                           \
    const float* lb = buf[BUFI];                                              \
    _Pragma("unroll 4")                                                       \
    for (int mm = 0; mm < 32; ++mm) {                                         \
      int p = (v4 ^ (mm & 7)) * 4;                                            \
      float4 gv = *(const float4*)&lb[mm * 128 + p];                          \
      float4 w4 = *(const float4*)&upool[((S) * 32 + mm) * 36 + h0v];         \
      a0.x += w4.x*gv.x; a0.y += w4.x*gv.y; a0.z += w4.x*gv.z; a0.w += w4.x*gv.w; \
      a1.x += w4.y*gv.x; a1.y += w4.y*gv.y; a1.z += w4.y*gv.z; a1.w += w4.y*gv.w; \
      a2.x += w4.z*gv.x; a2.y += w4.z*gv.y; a2.z += w4.z*gv.z; a2.w += w4.z*gv.w; \
      a3.x += w4.w*gv.x; a3.y += w4.w*gv.y; a3.z += w4.w*gv.z; a3.w += w4.w*gv.w; \
    }                                                                         \
  }

  // ---- K phase ----
  stage_issue(kbase, kapp, buf[1], m0 + 32, t);     // K1
  WAITVL(4); BAR();                                 // K0 ready (K1 in flight)
  LOGITS_TILE(0, 0);
  copy_out(buf[0], kc, m0, t);                      // S0 (+4 stores)
  WAITL(); BAR();

  stage_issue(kbase, kapp, buf[0], m0 + 64, t);     // K2
  WAITVL(8); BAR();                                 // K1 ready (S0+K2 newer)
  LOGITS_TILE(1, 1);
  copy_out(buf[1], kc, m0 + 32, t);                 // S1
  WAITL(); BAR();

  stage_issue(kbase, kapp, buf[1], m0 + 96, t);     // K3
  WAITVL(8); BAR();                                 // K2 ready (S1+K3 newer)
  LOGITS_TILE(2, 0);
  copy_out(buf[0], kc, m0 + 64, t);                 // S2
  WAITL(); BAR();

  stage_issue(vbase, vapp, buf[0], m0, t);          // V0
  WAITVL(8); BAR();                                 // K3 ready (S2+V0 newer)
  LOGITS_TILE(3, 1);
  copy_out(buf[1], kc, m0 + 96, t);                 // S3
  WAITL(); BAR();   // all qs reads done -> upool becomes wl

  // ---- in-register softmax over the 16-lane mg-group ----
  {
    float mx0 = -3.402823466e38f, mx1 = -3.402823466e38f;
    #pragma unroll
    for (int j = 0; j < 8; ++j) {
      mx0 = fmaxf(mx0, accL0[j]);
      mx1 = fmaxf(mx1, accL1[j]);
    }
    #pragma unroll
    for (int off = 1; off <= 8; off <<= 1) {
      mx0 = fmaxf(mx0, __shfl_xor(mx0, off));
      mx1 = fmaxf(mx1, __shfl_xor(mx1, off));
    }
    float s0 = 0.f, s1 = 0.f;
    #pragma unroll
    for (int j = 0; j < 8; ++j) {
      float e0 = exp2f((accL0[j] - mx0) * LOG2E); accL0[j] = e0; s0 += e0;
      float e1 = exp2f((accL1[j] - mx1) * LOG2E); accL1[j] = e1; s1 += e1;
    }
    #pragma unroll
    for (int off = 1; off <= 8; off <<= 1) {
      s0 += __shfl_xor(s0, off);
      s1 += __shfl_xor(s1, off);
    }
    #pragma unroll
    for (int s = 0; s < 4; ++s)
      #pragma unroll
      for (int i = 0; i < 2; ++i) {
        int m = s * 32 + mg + 16 * i;
        upool[m * 36 + h0]     = accL0[s * 2 + i];
        upool[m * 36 + h0 + 1] = accL1[s * 2 + i];
      }
    if (mg == 0) {   // 2 stores per wave -> vmcnt +2
      size_t sb0 = (((size_t)b * H_ + h0) * NCHUNK + chunk) * 2;
      *(float2*)&stats[sb0] = make_float2(mx0, s0);
      size_t sb1 = (((size_t)b * H_ + h0 + 1) * NCHUNK + chunk) * 2;
      *(float2*)&stats[sb1] = make_float2(mx1, s1);
    }
  }
  WAITL(); BAR();   // wl visible

  // ---- V phase ----
  float4 a0 = {0,0,0,0}, a1 = {0,0,0,0}, a2 = {0,0,0,0}, a3 = {0,0,0,0};

  stage_issue(vbase, vapp, buf[1], m0 + 32, t);     // V1
  WAITVL(10); BAR();                                // V0 ready (S3+stats+V1 = 10 newer)
  PV_TILE(0, 0);
  copy_out(buf[0], vc, m0, t);                      // S4
  WAITL(); BAR();

  stage_issue(vbase, vapp, buf[0], m0 + 64, t);     // V2
  WAITVL(8); BAR();                                 // V1 ready (S4+V2 newer)
  PV_TILE(1, 1);
  copy_out(buf[1], vc, m0 + 32, t);                 // S5
  WAITL(); BAR();

  stage_issue(vbase, vapp, buf[1], m0 + 96, t);     // V3
  WAITVL(8); BAR();                                 // V2 ready (S5+V3 newer)
  PV_TILE(2, 0);
  copy_out(buf[0], vc, m0 + 64, t);                 // S6
  WAITL(); BAR();

  WAITVL(4); BAR();                                 // V3 ready (S6 newer)
  PV_TILE(3, 1);
  copy_out(buf[1], vc, m0 + 96, t);                 // S7

  size_t base = ((size_t)(chunk * B_ + b) * H_ + h0v) * VD + v4 * 4;
  *(float4*)&o_part[base]          = a0;
  *(float4*)&o_part[base + VD]     = a1;
  *(float4*)&o_part[base + 2 * VD] = a2;
  *(float4*)&o_part[base + 3 * VD] = a3;
#undef LOGITS_TILE
#undef PV_TILE
}

// ---------------- K3: flash combine -> o -----------------------------------
__global__ __launch_bounds__(128) void k_combine(
    const float* __restrict__ o_part, const float* __restrict__ stats,
    float* __restrict__ o) {
  const int bh = blockIdx.x;
  const int t = threadIdx.x;
  __shared__ float st[64];
  if (t < 64) st[t] = stats[(size_t)bh * 64 + t];
  __syncthreads();
  float M = -3.402823466e38f;
  #pragma unroll
  for (int c = 0; c < NCHUNK; ++c) M = fmaxf(M, st[2 * c]);
  float wc[NCHUNK];
  float denom = 0.f;
  #pragma unroll
  for (int c = 0; c < NCHUNK; ++c) {
    float e = exp2f((st[2 * c] - M) * LOG2E);
    wc[c] = e;
    denom += st[2 * c + 1] * e;
  }
  const float inv = 1.0f / denom;
  const int b = bh >> 5, h = bh & 31;
  float acc = 0.f;
  #pragma unroll 4
  for (int c = 0; c < NCHUNK; ++c)
    acc += wc[c] * o_part[((size_t)(c * B_ + b) * H_ + h) * VD + t];
  o[(size_t)bh * VD + t] = acc * inv;
}

// ---------------- K5: partial y = o . Wo -----------------------------------
__global__ __launch_bounds__(256) void k_out_partial(
    const float* __restrict__ o, const float* __restrict__ Wo,
    float* __restrict__ Py) {
  __shared__ float os[64][260];   // padded
  const int dc = blockIdx.x;
  const int hvc = blockIdx.y;
  const int t = threadIdx.x;
  #pragma unroll
  for (int j = 0; j < 16; ++j) {
    int f = t + 256 * j;
    int row = f >> 6, c4 = f & 63;
    *(float4*)&os[row][c4 * 4] =
        *(const float4*)(o + (size_t)row * 4096 + hvc * 256 + c4 * 4);
  }
  __syncthreads();
  const int bq = t >> 4, dg = t & 15;
  const int b0 = bq * 4;
  const float* wp = Wo + (size_t)(hvc * 256) * D_ + dc * 128 + dg * 8;
  float acc[4][8];
  #pragma unroll
  for (int i = 0; i < 4; ++i)
    #pragma unroll
    for (int j = 0; j < 8; ++j) acc[i][j] = 0.f;
  #pragma unroll 8
  for (int hv = 0; hv < 256; ++hv) {
    float4 w0 = *(const float4*)(wp + (size_t)hv * D_);
    float4 w1 = *(const float4*)(wp + (size_t)hv * D_ + 4);
    float ov[4];
    #pragma unroll
    for (int i = 0; i < 4; ++i) ov[i] = os[b0 + i][hv];
    #pragma unroll
    for (int i = 0; i < 4; ++i) {
      acc[i][0] += ov[i] * w0.x; acc[i][1] += ov[i] * w0.y;
      acc[i][2] += ov[i] * w0.z; acc[i][3] += ov[i] * w0.w;
      acc[i][4] += ov[i] * w1.x; acc[i][5] += ov[i] * w1.y;
      acc[i][6] += ov[i] * w1.z; acc[i][7] += ov[i] * w1.w;
    }
  }
  #pragma unroll
  for (int i = 0; i < 4; ++i) {
    size_t base = ((size_t)hvc * 64 + b0 + i) * 4096 + dc * 128 + dg * 8;
    *(float4*)&Py[base]     = make_float4(acc[i][0], acc[i][1], acc[i][2], acc[i][3]);
    *(float4*)&Py[base + 4] = make_float4(acc[i][4], acc[i][5], acc[i][6], acc[i][7]);
  }
}

// ---------------- K5b: reduce partial y ------------------------------------
__global__ __launch_bounds__(256) void k_yreduce(
    const float* __restrict__ Py, float* __restrict__ y) {
  int i = blockIdx.x * 256 + threadIdx.x;
  float s = 0.f;
  #pragma unroll
  for (int c = 0; c < 16; ++c) s += Py[(size_t)c * 262144 + i];
  y[i] = s;
}

extern "C" void kernel_launch(void* const* d_in, const int* in_sizes, int n_in,
                              void* d_out, int out_size, void* d_ws, size_t ws_size,
                              hipStream_t stream) {
  const float* x     = (const float*)d_in[0];
  const float* prevK = (const float*)d_in[1];
  const float* prevV = (const float*)d_in[2];
  const float* Wq    = (const float*)d_in[3];
  const float* Wk    = (const float*)d_in[4];
  const float* Wv    = (const float*)d_in[5];
  const float* Wo    = (const float*)d_in[6];

  float* y  = (float*)d_out;
  float* Kc = y + (size_t)B_ * D_;
  float* Vc = Kc + (size_t)B_ * M1_ * KD;

  float* ws     = (float*)d_ws;
  float* P      = ws + WS_P;
  float* q      = ws + WS_Q;
  float* stats  = ws + WS_STATS;
  float* o      = ws + WS_O;
  float* o_part = ws + WS_OPART;

  k_proj_partial<<<dim3(16, 34), 256, 0, stream>>>(x, Wq, Wk, Wv, P);
  k_proj_reduce<<<1088, 256, 0, stream>>>(P, q, Kc, Vc);
  k_flash<<<dim3(32, 64), 256, 0, stream>>>(prevK, prevV, q, Kc, Vc, o_part, stats);
  k_combine<<<2048, 128, 0, stream>>>(o_part, stats, o);
  k_out_partial<<<dim3(32, 16), 256, 0, stream>>>(o, Wo, P);
  k_yreduce<<<1024, 256, 0, stream>>>(P, y);
}